// Round 1
// baseline (236.533 us; speedup 1.0000x reference)
//
#include <hip/hip_runtime.h>

constexpr int Bn = 8, Cn = 3, Hn = 720, Wn = 1280;
constexpr int HW = Hn * Wn;
constexpr long long NPIX = (long long)Bn * HW;          // 7,372,800
constexpr long long NTOT = (long long)Bn * Cn * HW;     // 22,118,400

__device__ __forceinline__ float bilin(const float* __restrict__ base,
                                       int i00, int i01, int i10, int i11,
                                       float wx, float wy) {
    float v00 = base[i00], v01 = base[i01], v10 = base[i10], v11 = base[i11];
    float top = fmaf(wx, v01 - v00, v00);
    float bot = fmaf(wx, v11 - v10, v10);
    return fmaf(wy, bot - top, top);
}

__global__ __launch_bounds__(256) void warp_loss_kernel(
        const float* __restrict__ L,
        const float* __restrict__ R,
        const float* __restrict__ Flm,
        const float* __restrict__ Frm,
        const float* __restrict__ G,
        double* __restrict__ accum) {
    float local = 0.f;
    const long long stride = (long long)gridDim.x * blockDim.x;
    for (long long i = (long long)blockIdx.x * blockDim.x + threadIdx.x;
         i < NPIX; i += stride) {
        const int b = (int)(i / HW);
        const int p = (int)(i - (long long)b * HW);
        const int y = p / Wn;
        const int x = p - y * Wn;

        const float* fl = Flm + (size_t)b * 2 * HW;
        const float* fr = Frm + (size_t)b * 2 * HW;
        // clip to [0, W-1] / [0, H-1] (border padding, align_corners pixel coords)
        const float xl = fminf(fmaxf((float)x + fl[p],      0.f), (float)(Wn - 1));
        const float yl = fminf(fmaxf((float)y + fl[HW + p], 0.f), (float)(Hn - 1));
        const float xr = fminf(fmaxf((float)x + fr[p],      0.f), (float)(Wn - 1));
        const float yr = fminf(fmaxf((float)y + fr[HW + p], 0.f), (float)(Hn - 1));

        const float x0lf = floorf(xl), y0lf = floorf(yl);
        const float wxl = xl - x0lf,   wyl = yl - y0lf;
        const int x0l = (int)x0lf, y0l = (int)y0lf;
        const int x1l = min(x0l + 1, Wn - 1), y1l = min(y0l + 1, Hn - 1);
        const int l00 = y0l * Wn + x0l, l01 = y0l * Wn + x1l;
        const int l10 = y1l * Wn + x0l, l11 = y1l * Wn + x1l;

        const float x0rf = floorf(xr), y0rf = floorf(yr);
        const float wxr = xr - x0rf,   wyr = yr - y0rf;
        const int x0r = (int)x0rf, y0r = (int)y0rf;
        const int x1r = min(x0r + 1, Wn - 1), y1r = min(y0r + 1, Hn - 1);
        const int r00 = y0r * Wn + x0r, r01 = y0r * Wn + x1r;
        const int r10 = y1r * Wn + x0r, r11 = y1r * Wn + x1r;

        const float* Lb = L + (size_t)b * Cn * HW;
        const float* Rb = R + (size_t)b * Cn * HW;
        const float* Gb = G + (size_t)b * Cn * HW;
        #pragma unroll
        for (int c = 0; c < Cn; ++c) {
            const float g  = Gb[c * HW + p];
            const float sL = bilin(Lb + c * HW, l00, l01, l10, l11, wxl, wyl);
            const float sR = bilin(Rb + c * HW, r00, r01, r10, r11, wxr, wyr);
            local += fabsf(sL - g) + fabsf(sR - g);
        }
    }

    // wave (64) shuffle reduce
    #pragma unroll
    for (int off = 32; off > 0; off >>= 1)
        local += __shfl_down(local, off, 64);

    __shared__ float wsum[4];
    const int lane = threadIdx.x & 63;
    const int wid  = threadIdx.x >> 6;
    if (lane == 0) wsum[wid] = local;
    __syncthreads();
    if (threadIdx.x == 0) {
        float s = wsum[0] + wsum[1] + wsum[2] + wsum[3];
        atomicAdd(accum, (double)s);
    }
}

__global__ void finalize_kernel(const double* __restrict__ accum,
                                float* __restrict__ out) {
    out[0] = (float)(accum[0] / (double)NTOT);
}

extern "C" void kernel_launch(void* const* d_in, const int* in_sizes, int n_in,
                              void* d_out, int out_size, void* d_ws, size_t ws_size,
                              hipStream_t stream) {
    const float* L   = (const float*)d_in[0];
    const float* R   = (const float*)d_in[1];
    const float* flm = (const float*)d_in[2];
    const float* frm = (const float*)d_in[3];
    const float* gt  = (const float*)d_in[4];
    double* accum = (double*)d_ws;

    hipMemsetAsync(accum, 0, sizeof(double), stream);

    const int block = 256;
    const int grid  = 2048;   // ~8 blocks/CU, grid-stride over 7.37M pixels
    warp_loss_kernel<<<grid, block, 0, stream>>>(L, R, flm, frm, gt, accum);
    finalize_kernel<<<1, 1, 0, stream>>>(accum, (float*)d_out);
}